// Round 6
// baseline (257.686 us; speedup 1.0000x reference)
//
#include <hip/hip_runtime.h>

#define IN_DIM 128
#define F1 256      // HEADS*HID = 4*64
#define HID 64
#define OUT_DIM 32
#define NEG 0.2f
#define PADK 136    // LDS row pitch in bf16 elems (128 + 8): frag reads 2-way alias = free

typedef __attribute__((ext_vector_type(8))) short short8;
typedef __attribute__((ext_vector_type(4))) float v4f;
typedef __attribute__((ext_vector_type(2))) float v2f;

// ---- bf16 helpers ----
__device__ __forceinline__ float b2fl(unsigned u) {
  union { unsigned i; float f; } c; c.i = u << 16; return c.f;
}
__device__ __forceinline__ float b2fh(unsigned u) {
  union { unsigned i; float f; } c; c.i = u & 0xffff0000u; return c.f;
}
__device__ __forceinline__ unsigned short f2b(float f) {
  union { float f; unsigned i; } c; c.f = f;
  unsigned r = c.i + 0x7fffu + ((c.i >> 16) & 1u);   // RNE
  return (unsigned short)(r >> 16);
}

// ---- merged prep + hist ----
__global__ __launch_bounds__(256) void k_prep_hist(const float* __restrict__ W1,
    unsigned short* __restrict__ W1t, const float* __restrict__ W2,
    unsigned short* __restrict__ W2t, const int* __restrict__ adj,
    int* __restrict__ cnt, int* __restrict__ rank, int E_, int n) {
  const int b = blockIdx.x;
  if (b < 128) {            // W1t[n][k] = W1[k][n], 32768 elems
    int idx = b * 256 + threadIdx.x;
    int nn = idx >> 7, k = idx & 127;
    W1t[idx] = f2b(W1[(size_t)k * F1 + nn]);
    return;
  }
  if (b < 160) {            // W2t[n][k] = W2[k][n], 8192 elems
    int idx = (b - 128) * 256 + threadIdx.x;
    int nn = idx >> 8, k = idx & 255;
    W2t[idx] = f2b(W2[(size_t)k * OUT_DIM + nn]);
    return;
  }
  int e = (b - 160) * 256 + threadIdx.x;
  int ET = E_ + n;
  if (e >= ET) return;
  int d = (e < E_) ? adj[E_ + e] : (e - E_);
  rank[e] = atomicAdd(&cnt[d], 1);
}

// ------- GEMM1 via MFMA: h1f8[N,256](fp8 e4m3) = bf16(x)[N,128] @ W1[128,256] -------
// LDS-staged W per head (R4: direct-global W frags serialized 200-cyc L2 loads
// into the MFMA chain at ~2 blocks/CU -> 45 µs vs 25 µs staged).
__global__ __launch_bounds__(256) void k_gemm1(const float* __restrict__ x,
    const unsigned short* __restrict__ W1t,
    const float* __restrict__ a1s_w, const float* __restrict__ a1d_w,
    unsigned char* __restrict__ h1f8, float* __restrict__ as1,
    float* __restrict__ ad1, int n) {
  __shared__ unsigned short xs[64 * PADK];   // 17.4 KB
  __shared__ unsigned short ws[64 * PADK];   // 17.4 KB (reused per head)
  const int tid = threadIdx.x;
  const int rb = blockIdx.x * 64;

#pragma unroll
  for (int i = 0; i < 8; ++i) {
    int idx = tid + i * 256;
    int row = idx >> 5, c4 = idx & 31;
    float4 v = make_float4(0.f, 0.f, 0.f, 0.f);
    if (rb + row < n) v = *(const float4*)&x[(size_t)(rb + row) * IN_DIM + c4 * 4];
    ushort4 b; b.x = f2b(v.x); b.y = f2b(v.y); b.z = f2b(v.z); b.w = f2b(v.w);
    *(ushort4*)&xs[row * PADK + c4 * 4] = b;
  }

  const int wv = tid >> 6;
  const int lane = tid & 63;
  const int l15 = lane & 15, quad = lane >> 4;

  for (int head = 0; head < 4; ++head) {
    const int cb = head * 64;
#pragma unroll
    for (int i = 0; i < 4; ++i) {
      int idx = tid + i * 256;
      int row = idx >> 4, c = idx & 15;
      *(uint4*)&ws[row * PADK + c * 8] =
          *(const uint4*)&W1t[(size_t)(cb + row) * IN_DIM + c * 8];
    }
    __syncthreads();

    v4f acc0 = {0.f, 0.f, 0.f, 0.f}, acc1 = acc0, acc2 = acc0, acc3 = acc0;
#pragma unroll
    for (int kt = 0; kt < 4; ++kt) {
      const int ko = kt * 32 + quad * 8;
      short8 af = *(const short8*)&xs[(wv * 16 + l15) * PADK + ko];
      short8 b0 = *(const short8*)&ws[(l15) * PADK + ko];
      short8 b1 = *(const short8*)&ws[(16 + l15) * PADK + ko];
      short8 b2 = *(const short8*)&ws[(32 + l15) * PADK + ko];
      short8 b3 = *(const short8*)&ws[(48 + l15) * PADK + ko];
      acc0 = __builtin_amdgcn_mfma_f32_16x16x32_bf16(af, b0, acc0, 0, 0, 0);
      acc1 = __builtin_amdgcn_mfma_f32_16x16x32_bf16(af, b1, acc1, 0, 0, 0);
      acc2 = __builtin_amdgcn_mfma_f32_16x16x32_bf16(af, b2, acc2, 0, 0, 0);
      acc3 = __builtin_amdgcn_mfma_f32_16x16x32_bf16(af, b3, acc3, 0, 0, 0);
    }

    const float s0 = a1s_w[cb + l15],      s1 = a1s_w[cb + 16 + l15];
    const float s2 = a1s_w[cb + 32 + l15], s3 = a1s_w[cb + 48 + l15];
    const float d0 = a1d_w[cb + l15],      d1 = a1d_w[cb + 16 + l15];
    const float d2 = a1d_w[cb + 32 + l15], d3 = a1d_w[cb + 48 + l15];
#pragma unroll
    for (int r = 0; r < 4; ++r) {
      const int row = rb + wv * 16 + quad * 4 + r;
      const bool ok = row < n;
      if (ok) {
        size_t base = (size_t)row * F1 + cb;
        int pA = __builtin_amdgcn_cvt_pk_fp8_f32(acc0[r], acc1[r], 0, false);
        int pB = __builtin_amdgcn_cvt_pk_fp8_f32(acc2[r], acc3[r], 0, false);
        h1f8[base + l15]      = (unsigned char)(pA & 0xff);
        h1f8[base + 16 + l15] = (unsigned char)((pA >> 8) & 0xff);
        h1f8[base + 32 + l15] = (unsigned char)(pB & 0xff);
        h1f8[base + 48 + l15] = (unsigned char)((pB >> 8) & 0xff);
      }
      float ds = acc0[r] * s0 + acc1[r] * s1 + acc2[r] * s2 + acc3[r] * s3;
      float dd = acc0[r] * d0 + acc1[r] * d1 + acc2[r] * d2 + acc3[r] * d3;
#pragma unroll
      for (int m = 1; m <= 8; m <<= 1) {
        ds += __shfl_xor(ds, m, 64);
        dd += __shfl_xor(dd, m, 64);
      }
      if (ok && l15 == 0) {
        as1[(size_t)row * 4 + head] = ds;
        ad1[(size_t)row * 4 + head] = dd;
      }
    }
    __syncthreads();   // ws reuse barrier (LDS reads done before next stage)
  }
}

// scan phase A: per-1024-chunk local exclusive scan + chunk sums; block 0 also
// zeroes gsum/gcnt (consumed by k_pool much later).
__global__ __launch_bounds__(256) void k_scan_local(const int* __restrict__ cnt,
    int* __restrict__ offs, int* __restrict__ bsum,
    float* __restrict__ gsum, float* __restrict__ gcnt, int n) {
  __shared__ int wsums[4];
  const int tid = threadIdx.x;
  if (blockIdx.x == 0 && tid < 64) { gsum[tid] = 0.f; gcnt[tid] = 0.f; }
  const int lane = tid & 63, w = tid >> 6;
  const int base = blockIdx.x * 1024;
  const int i0 = base + tid * 4;
  int v[4];
#pragma unroll
  for (int k = 0; k < 4; ++k) { int i = i0 + k; v[k] = (i < n) ? cnt[i] : 0; }
  int tsum = v[0] + v[1] + v[2] + v[3];
  int incl = tsum;
#pragma unroll
  for (int d = 1; d < 64; d <<= 1) {
    int t = __shfl_up(incl, (unsigned)d, 64);
    if (lane >= d) incl += t;
  }
  if (lane == 63) wsums[w] = incl;
  __syncthreads();
  int pre = 0;
  for (int k = 0; k < w; ++k) pre += wsums[k];
  int run = pre + incl - tsum;
#pragma unroll
  for (int k = 0; k < 4; ++k) { int i = i0 + k; if (i < n) offs[i] = run; run += v[k]; }
  if (tid == 255) bsum[blockIdx.x] = pre + incl;
}

// scan phase B (merged bsum-scan + add)
__global__ __launch_bounds__(256) void k_scan_add(int* __restrict__ offs,
    const int* __restrict__ bsum, int n, int nb) {
  __shared__ int pre_s, tot_s;
  const int tid = threadIdx.x;
  if (tid < 64) {
    int v = (tid < nb) ? bsum[tid] : 0;
    int incl = v;
#pragma unroll
    for (int d = 1; d < 64; d <<= 1) {
      int t = __shfl_up(incl, (unsigned)d, 64);
      if (tid >= d) incl += t;
    }
    int excl = incl - v;
    int pre = __shfl(excl, blockIdx.x >> 2, 64);
    int tot = __shfl(incl, nb - 1, 64);
    if (tid == 0) { pre_s = pre; tot_s = tot; }
  }
  __syncthreads();
  int i = blockIdx.x * 256 + tid;
  if (i < n) offs[i] += pre_s;
  if (blockIdx.x == 0 && tid == 0) offs[n] = tot_s;
}

// -------- scatter, atomic-free; record = src only (4B). Weights are computed
// inline in the agg kernels (ad*[dst] is wave-uniform there). 4 dst-bins.
__global__ __launch_bounds__(256) void k_scatter(const int* __restrict__ adj,
    const int* __restrict__ rank, const int* __restrict__ offs,
    int* __restrict__ csrsrc, int E_, int n, int binw) {
  const int bin = blockIdx.x & 3;
  const int chunk = blockIdx.x >> 2;
  const int e = chunk * 256 + threadIdx.x;
  const int ET = E_ + n;
  if (e >= ET) return;
  int d = (e < E_) ? adj[E_ + e] : (e - E_);
  const int lo = bin * binw;
  if (d < lo || d >= lo + binw) return;   // not my bin
  int s = (e < E_) ? adj[e] : d;
  int pos = offs[d] + rank[e];
  csrsrc[pos] = s;
}

// fp8 row accumulate: 8 packed-pair FMAs off the packed cvt_pk_f32_fp8 results.
__device__ __forceinline__ void acc8_fp8(v2f acc[8], const uint4 u, float w) {
  v2f w2; w2.x = w; w2.y = w;
  acc[0] += w2 * __builtin_amdgcn_cvt_pk_f32_fp8(u.x, false);
  acc[1] += w2 * __builtin_amdgcn_cvt_pk_f32_fp8(u.x, true);
  acc[2] += w2 * __builtin_amdgcn_cvt_pk_f32_fp8(u.y, false);
  acc[3] += w2 * __builtin_amdgcn_cvt_pk_f32_fp8(u.y, true);
  acc[4] += w2 * __builtin_amdgcn_cvt_pk_f32_fp8(u.z, false);
  acc[5] += w2 * __builtin_amdgcn_cvt_pk_f32_fp8(u.z, true);
  acc[6] += w2 * __builtin_amdgcn_cvt_pk_f32_fp8(u.w, false);
  acc[7] += w2 * __builtin_amdgcn_cvt_pk_f32_fp8(u.w, true);
}

// ------- fused GAT layer 1 (fp8 gather, quarter-wave per edge, inline weights) -------
// R6: main-16 (4 independent edge chains in flight per lane) + ONE predicated
// 16-wide tail. Serial dependent phases per node 3->2 at deg~17 (latency-bound
// per R5 post-mortem: VALU cut was neutral, VALUBusy 61%, hbm 35%).
__global__ __launch_bounds__(256) void k_agg1(const unsigned char* __restrict__ h1f8,
    const int* __restrict__ offs, const int* __restrict__ csrsrc,
    const float* __restrict__ as1, const float* __restrict__ ad1,
    const float* __restrict__ b1, unsigned short* __restrict__ relu1b, int n) {
  int node = blockIdx.x * 4 + (threadIdx.x >> 6);
  int lane = threadIdx.x & 63;
  if (node >= n) return;
  const int sub = lane >> 4;       // edge slot within group of 4
  const int p = lane & 15;         // feature 16-tuple
  const int h = p >> 2;            // head
  const float ad1n = ad1[(size_t)node * 4 + h];   // dst term: wave-uniform per head
  const int j0 = offs[node], j1 = offs[node + 1];
  v2f acc[8];
#pragma unroll
  for (int i = 0; i < 8; ++i) { acc[i].x = 0.f; acc[i].y = 0.f; }
  float den = 0.f;
  int j = j0;
  for (; j + 16 <= j1; j += 16) {
    const int s0 = csrsrc[j + sub];
    const int s1 = csrsrc[j + 4 + sub];
    const int s2 = csrsrc[j + 8 + sub];
    const int s3 = csrsrc[j + 12 + sub];
    const uint4 u0 = ((const uint4*)(h1f8 + (size_t)s0 * F1))[p];
    const uint4 u1 = ((const uint4*)(h1f8 + (size_t)s1 * F1))[p];
    const uint4 u2 = ((const uint4*)(h1f8 + (size_t)s2 * F1))[p];
    const uint4 u3 = ((const uint4*)(h1f8 + (size_t)s3 * F1))[p];
    float e0 = as1[(size_t)s0 * 4 + h] + ad1n; e0 = (e0 >= 0.f) ? e0 : NEG * e0;
    float e1 = as1[(size_t)s1 * 4 + h] + ad1n; e1 = (e1 >= 0.f) ? e1 : NEG * e1;
    float e2 = as1[(size_t)s2 * 4 + h] + ad1n; e2 = (e2 >= 0.f) ? e2 : NEG * e2;
    float e3 = as1[(size_t)s3 * 4 + h] + ad1n; e3 = (e3 >= 0.f) ? e3 : NEG * e3;
    const float w0 = __expf(e0);
    const float w1 = __expf(e1);
    const float w2 = __expf(e2);
    const float w3 = __expf(e3);
    den += w0; acc8_fp8(acc, u0, w0);
    den += w1; acc8_fp8(acc, u1, w1);
    den += w2; acc8_fp8(acc, u2, w2);
    den += w3; acc8_fp8(acc, u3, w3);
  }
  if (j < j1) {   // predicated 16-wide tail: handles remaining 1..15 in one phase
    const int i0 = j + sub,      i1 = j + 4 + sub;
    const int i2 = j + 8 + sub,  i3 = j + 12 + sub;
    const bool v0 = i0 < j1, v1 = i1 < j1, v2 = i2 < j1, v3 = i3 < j1;
    const int s0 = csrsrc[v0 ? i0 : (j1 - 1)];
    const int s1 = csrsrc[v1 ? i1 : (j1 - 1)];
    const int s2 = csrsrc[v2 ? i2 : (j1 - 1)];
    const int s3 = csrsrc[v3 ? i3 : (j1 - 1)];
    const uint4 u0 = ((const uint4*)(h1f8 + (size_t)s0 * F1))[p];
    const uint4 u1 = ((const uint4*)(h1f8 + (size_t)s1 * F1))[p];
    const uint4 u2 = ((const uint4*)(h1f8 + (size_t)s2 * F1))[p];
    const uint4 u3 = ((const uint4*)(h1f8 + (size_t)s3 * F1))[p];
    float e0 = as1[(size_t)s0 * 4 + h] + ad1n; e0 = (e0 >= 0.f) ? e0 : NEG * e0;
    float e1 = as1[(size_t)s1 * 4 + h] + ad1n; e1 = (e1 >= 0.f) ? e1 : NEG * e1;
    float e2 = as1[(size_t)s2 * 4 + h] + ad1n; e2 = (e2 >= 0.f) ? e2 : NEG * e2;
    float e3 = as1[(size_t)s3 * 4 + h] + ad1n; e3 = (e3 >= 0.f) ? e3 : NEG * e3;
    const float w0 = v0 ? __expf(e0) : 0.f;
    const float w1 = v1 ? __expf(e1) : 0.f;
    const float w2 = v2 ? __expf(e2) : 0.f;
    const float w3 = v3 ? __expf(e3) : 0.f;
    den += w0; acc8_fp8(acc, u0, w0);
    den += w1; acc8_fp8(acc, u1, w1);
    den += w2; acc8_fp8(acc, u2, w2);
    den += w3; acc8_fp8(acc, u3, w3);
  }
  den += __shfl_xor(den, 16, 64); den += __shfl_xor(den, 32, 64);
#pragma unroll
  for (int i = 0; i < 8; ++i) {
    acc[i].x += __shfl_xor(acc[i].x, 16, 64);
    acc[i].x += __shfl_xor(acc[i].x, 32, 64);
    acc[i].y += __shfl_xor(acc[i].y, 16, 64);
    acc[i].y += __shfl_xor(acc[i].y, 32, 64);
  }
  if (sub == 0) {
    const float inv = 1.0f / den;
    float a[16];
#pragma unroll
    for (int i = 0; i < 8; ++i) { a[2 * i] = acc[i].x; a[2 * i + 1] = acc[i].y; }
    ushort4 r0, r1, r2, r3;
    const float4 bb0 = ((const float4*)b1)[4 * p + 0];
    const float4 bb1 = ((const float4*)b1)[4 * p + 1];
    const float4 bb2 = ((const float4*)b1)[4 * p + 2];
    const float4 bb3 = ((const float4*)b1)[4 * p + 3];
    r0.x = f2b(fmaxf(a[0] * inv + bb0.x, 0.f));
    r0.y = f2b(fmaxf(a[1] * inv + bb0.y, 0.f));
    r0.z = f2b(fmaxf(a[2] * inv + bb0.z, 0.f));
    r0.w = f2b(fmaxf(a[3] * inv + bb0.w, 0.f));
    r1.x = f2b(fmaxf(a[4] * inv + bb1.x, 0.f));
    r1.y = f2b(fmaxf(a[5] * inv + bb1.y, 0.f));
    r1.z = f2b(fmaxf(a[6] * inv + bb1.z, 0.f));
    r1.w = f2b(fmaxf(a[7] * inv + bb1.w, 0.f));
    r2.x = f2b(fmaxf(a[8] * inv + bb2.x, 0.f));
    r2.y = f2b(fmaxf(a[9] * inv + bb2.y, 0.f));
    r2.z = f2b(fmaxf(a[10] * inv + bb2.z, 0.f));
    r2.w = f2b(fmaxf(a[11] * inv + bb2.w, 0.f));
    r3.x = f2b(fmaxf(a[12] * inv + bb3.x, 0.f));
    r3.y = f2b(fmaxf(a[13] * inv + bb3.y, 0.f));
    r3.z = f2b(fmaxf(a[14] * inv + bb3.z, 0.f));
    r3.w = f2b(fmaxf(a[15] * inv + bb3.w, 0.f));
    size_t base = (size_t)node * F1 + 16 * p;
    *(ushort4*)&relu1b[base + 0]  = r0;
    *(ushort4*)&relu1b[base + 4]  = r1;
    *(ushort4*)&relu1b[base + 8]  = r2;
    *(ushort4*)&relu1b[base + 12] = r3;
  }
}

// ---- GEMM2 via MFMA: h2[N,32] = relu1b(bf16) @ W2t(bf16); fused alpha2 dots ----
__global__ __launch_bounds__(256) void k_gemm2(const unsigned short* __restrict__ relu1b,
    const unsigned short* __restrict__ W2t, const float* __restrict__ a2s_w,
    const float* __restrict__ a2d_w, unsigned short* __restrict__ h2b,
    float* __restrict__ as2, float* __restrict__ ad2, int n) {
  const int tid = threadIdx.x;
  const int wv = tid >> 6, lane = tid & 63;
  const int l15 = lane & 15, quad = lane >> 4;
  const int row0 = blockIdx.x * 64 + wv * 16;
  v4f acc0 = {0.f, 0.f, 0.f, 0.f}, acc1 = acc0;
  const int arow = row0 + l15;
  const bool aok = arow < n;
#pragma unroll
  for (int kt = 0; kt < 8; ++kt) {
    const int ko = kt * 32 + quad * 8;
    short8 af = {0, 0, 0, 0, 0, 0, 0, 0};
    if (aok) af = *(const short8*)&relu1b[(size_t)arow * F1 + ko];
    short8 b0 = *(const short8*)&W2t[(size_t)l15 * F1 + ko];
    short8 b1 = *(const short8*)&W2t[(size_t)(16 + l15) * F1 + ko];
    acc0 = __builtin_amdgcn_mfma_f32_16x16x32_bf16(af, b0, acc0, 0, 0, 0);
    acc1 = __builtin_amdgcn_mfma_f32_16x16x32_bf16(af, b1, acc1, 0, 0, 0);
  }
  const float s0 = a2s_w[l15], s1 = a2s_w[16 + l15];
  const float d0 = a2d_w[l15], d1 = a2d_w[16 + l15];
#pragma unroll
  for (int r = 0; r < 4; ++r) {
    const int row = row0 + quad * 4 + r;
    const bool ok = row < n;
    if (ok) {
      h2b[(size_t)row * OUT_DIM + l15]      = f2b(acc0[r]);
      h2b[(size_t)row * OUT_DIM + 16 + l15] = f2b(acc1[r]);
    }
    float ss = acc0[r] * s0 + acc1[r] * s1;
    float sd = acc0[r] * d0 + acc1[r] * d1;
#pragma unroll
    for (int m = 1; m <= 8; m <<= 1) {
      ss += __shfl_xor(ss, m, 64);
      sd += __shfl_xor(sd, m, 64);
    }
    if (ok && l15 == 0) { as2[row] = ss; ad2[row] = sd; }
  }
}

// -------- fused GAT layer 2 + log_softmax + lin -> per-node score --------
// 8-lane edge groups (uint2 row loads); R6: merged predicated A/B tail
// (one phase instead of up to two serial tail trips).
__global__ __launch_bounds__(256) void k_agg2(const unsigned short* __restrict__ h2b,
    const int* __restrict__ csrsrc, const int* __restrict__ offs,
    const float* __restrict__ as2, const float* __restrict__ ad2,
    const float* __restrict__ b2, const float* __restrict__ linW,
    float* __restrict__ score, int n) {
  int node = blockIdx.x * 4 + (threadIdx.x >> 6);
  int lane = threadIdx.x & 63;
  if (node >= n) return;
  const int grp = lane >> 3;      // edge slot within group of 8
  const int p = lane & 7;         // dword-pair index (dims 4p..4p+3)
  const float ad2n = ad2[node];   // dst term: wave-uniform
  const int j0 = offs[node], j1 = offs[node + 1];
  v2f aX = {0.f, 0.f}, aY = {0.f, 0.f};
  float den = 0.f;
  int jj = j0;
  for (; jj + 16 <= j1; jj += 16) {
    const int sA = csrsrc[jj + grp];
    const int sB = csrsrc[jj + 8 + grp];
    const uint2 uA = ((const uint2*)(h2b + (size_t)sA * OUT_DIM))[p];
    const uint2 uB = ((const uint2*)(h2b + (size_t)sB * OUT_DIM))[p];
    float ev;
    ev = as2[sA] + ad2n; ev = (ev >= 0.f) ? ev : NEG * ev;
    const float wA = __expf(ev);
    ev = as2[sB] + ad2n; ev = (ev >= 0.f) ? ev : NEG * ev;
    const float wB = __expf(ev);
    den += wA + wB;
    v2f wA2; wA2.x = wA; wA2.y = wA;
    v2f wB2; wB2.x = wB; wB2.y = wB;
    v2f vx, vy;
    vx.x = b2fl(uA.x); vx.y = b2fh(uA.x); aX += wA2 * vx;
    vy.x = b2fl(uA.y); vy.y = b2fh(uA.y); aY += wA2 * vy;
    vx.x = b2fl(uB.x); vx.y = b2fh(uB.x); aX += wB2 * vx;
    vy.x = b2fl(uB.y); vy.y = b2fh(uB.y); aY += wB2 * vy;
  }
  if (jj < j1) {   // predicated tail: up to 15 remaining in ONE phase
    const int iA = jj + grp,     iB = jj + 8 + grp;
    const bool vA = iA < j1,     vB = iB < j1;
    const int sA = csrsrc[vA ? iA : (j1 - 1)];
    const int sB = csrsrc[vB ? iB : (j1 - 1)];
    const uint2 uA = ((const uint2*)(h2b + (size_t)sA * OUT_DIM))[p];
    const uint2 uB = ((const uint2*)(h2b + (size_t)sB * OUT_DIM))[p];
    float ev;
    ev = as2[sA] + ad2n; ev = (ev >= 0.f) ? ev : NEG * ev;
    const float wA = vA ? __expf(ev) : 0.f;
    ev = as2[sB] + ad2n; ev = (ev >= 0.f) ? ev : NEG * ev;
    const float wB = vB ? __expf(ev) : 0.f;
    v2f wA2; wA2.x = wA; wA2.y = wA;
    v2f wB2; wB2.x = wB; wB2.y = wB;
    v2f vx, vy;
    den += wA;
    vx.x = b2fl(uA.x); vx.y = b2fh(uA.x); aX += wA2 * vx;
    vy.x = b2fl(uA.y); vy.y = b2fh(uA.y); aY += wA2 * vy;
    den += wB;
    vx.x = b2fl(uB.x); vx.y = b2fh(uB.x); aX += wB2 * vx;
    vy.x = b2fl(uB.y); vy.y = b2fh(uB.y); aY += wB2 * vy;
  }
  float a0 = aX.x, a1 = aX.y, a2 = aY.x, a3 = aY.y;
  // reduce across the 8 edge-groups (lane bits 3..5)
#pragma unroll
  for (int m = 8; m <= 32; m <<= 1) {
    den += __shfl_xor(den, m, 64);
    a0  += __shfl_xor(a0, m, 64);
    a1  += __shfl_xor(a1, m, 64);
    a2  += __shfl_xor(a2, m, 64);
    a3  += __shfl_xor(a3, m, 64);
  }
  const float inv = 1.0f / den;
  const float4 bb = ((const float4*)b2)[p];
  float o0 = a0 * inv + bb.x;
  float o1 = a1 * inv + bb.y;
  float o2 = a2 * inv + bb.z;
  float o3 = a3 * inv + bb.w;
  float m = fmaxf(fmaxf(o0, o1), fmaxf(o2, o3));
#pragma unroll
  for (int mm = 1; mm <= 4; mm <<= 1) m = fmaxf(m, __shfl_xor(m, mm, 64));
  float ssum = __expf(o0 - m) + __expf(o1 - m) + __expf(o2 - m) + __expf(o3 - m);
#pragma unroll
  for (int mm = 1; mm <= 4; mm <<= 1) ssum += __shfl_xor(ssum, mm, 64);
  const float lse = m + __logf(ssum);
  const float4 lw = ((const float4*)linW)[p];
  float sc = (o0 - lse) * lw.x + (o1 - lse) * lw.y + (o2 - lse) * lw.z + (o3 - lse) * lw.w;
#pragma unroll
  for (int mm = 1; mm <= 4; mm <<= 1) sc += __shfl_xor(sc, mm, 64);
  if (lane == 0) score[node] = sc;
}

// -------- pooling: LDS per-graph partials, few global atomics per block --------
// (two-stage on purpose: fusing atomics into k_agg2 serialized 100K RMWs onto
//  4 cachelines of gsum/gcnt -> +390 µs.)
__global__ __launch_bounds__(256) void k_pool(const float* __restrict__ score,
    const int* __restrict__ batch, float* __restrict__ gsum,
    float* __restrict__ gcnt, int n) {
  __shared__ float ps[64];
  __shared__ float pc[64];
  const int tid = threadIdx.x;
  if (tid < 64) { ps[tid] = 0.f; pc[tid] = 0.f; }
  __syncthreads();
  int i = blockIdx.x * 256 + tid;
  if (i < n) {
    int g = batch[i];
    atomicAdd(&ps[g], score[i]);
    atomicAdd(&pc[g], 1.0f);
  }
  __syncthreads();
  if (tid < 64 && pc[tid] != 0.f) {
    atomicAdd(&gsum[tid], ps[tid]);
    atomicAdd(&gcnt[tid], pc[tid]);
  }
}

__global__ void k_final(const float* __restrict__ gsum, const float* __restrict__ gcnt,
                        const float* __restrict__ linb, float* __restrict__ out, int g_) {
  int g = threadIdx.x;
  if (g < g_) out[g] = gsum[g] / fmaxf(gcnt[g], 1.0f) + linb[0];
}

extern "C" void kernel_launch(void* const* d_in, const int* in_sizes, int n_in,
                              void* d_out, int out_size, void* d_ws, size_t ws_size,
                              hipStream_t stream) {
  const float* x    = (const float*)d_in[0];
  const int*   adj  = (const int*)d_in[1];
  const int*   batch= (const int*)d_in[2];
  const float* W1   = (const float*)d_in[3];
  const float* a1s  = (const float*)d_in[4];
  const float* a1d  = (const float*)d_in[5];
  const float* b1   = (const float*)d_in[6];
  const float* W2   = (const float*)d_in[7];
  const float* a2s  = (const float*)d_in[8];
  const float* a2d  = (const float*)d_in[9];
  const float* b2   = (const float*)d_in[10];
  const float* linW = (const float*)d_in[11];
  const float* linb = (const float*)d_in[12];

  const int N = in_sizes[0] / IN_DIM;
  const int E = in_sizes[1] / 2;
  const int ET = E + N;
  const int G = out_size;   // 64
  const int NB = (N + 1023) / 1024;   // must be <= 64 for merged scan (N=50000 -> 49)
  const int BINW = (N + 3) / 4;

  char* wsb = (char*)d_ws;
  size_t off = 0;
  auto take = [&](size_t bytes) -> char* {
    char* p = wsb + off;
    off += (bytes + 255) & ~(size_t)255;
    return p;
  };
  unsigned char* h1f8  = (unsigned char*)take((size_t)N * F1);
  unsigned short* relu1b= (unsigned short*)take((size_t)N * F1 * 2);
  float* as1    = (float*)take((size_t)N * 4 * 4);
  float* ad1    = (float*)take((size_t)N * 4 * 4);
  unsigned short* h2b = (unsigned short*)take((size_t)N * OUT_DIM * 2);
  float* as2v   = (float*)take((size_t)N * 4);
  float* ad2v   = (float*)take((size_t)N * 4);
  float* score  = (float*)take((size_t)N * 4);
  int*   cnt    = (int*)take((size_t)N * 4);
  int*   offs   = (int*)take((size_t)(N + 1) * 4);
  int*   rank   = (int*)take((size_t)ET * 4);
  int*   csrsrc = (int*)take((size_t)ET * 4);
  int*   bsum   = (int*)take((size_t)(NB + 1) * 4);
  float* gsum   = (float*)take((size_t)G * 4);
  float* gcnt   = (float*)take((size_t)G * 4);
  unsigned short* W1t = (unsigned short*)take((size_t)IN_DIM * F1 * 2);
  unsigned short* W2t = (unsigned short*)take((size_t)F1 * OUT_DIM * 2);
  (void)ws_size; (void)n_in;

  hipMemsetAsync(cnt, 0, (size_t)N * 4, stream);

  dim3 b256(256);
  k_prep_hist<<<dim3(160 + (ET + 255) / 256), b256, 0, stream>>>(
      W1, W1t, W2, W2t, adj, cnt, rank, E, N);
  k_gemm1<<<dim3((N + 63) / 64), b256, 0, stream>>>(x, W1t, a1s, a1d, h1f8, as1, ad1, N);
  k_scan_local<<<dim3(NB), b256, 0, stream>>>(cnt, offs, bsum, gsum, gcnt, N);
  k_scan_add<<<dim3((N + 255) / 256), b256, 0, stream>>>(offs, bsum, N, NB);
  k_scatter<<<dim3(((ET + 255) / 256) * 4), b256, 0, stream>>>(adj, rank, offs, csrsrc, E, N, BINW);
  k_agg1<<<dim3((N + 3) / 4), b256, 0, stream>>>(h1f8, offs, csrsrc, as1, ad1, b1, relu1b, N);
  k_gemm2<<<dim3((N + 63) / 64), b256, 0, stream>>>(relu1b, W2t, a2s, a2d, h2b, as2v, ad2v, N);
  k_agg2<<<dim3((N + 3) / 4), b256, 0, stream>>>(h2b, csrsrc, offs, as2v, ad2v, b2, linW,
                                                 score, N);
  k_pool<<<dim3((N + 255) / 256), b256, 0, stream>>>(score, batch, gsum, gcnt, N);
  k_final<<<1, 64, 0, stream>>>(gsum, gcnt, linb, (float*)d_out, G);
}

// Round 7
// 244.756 us; speedup vs baseline: 1.0528x; 1.0528x over previous
//
#include <hip/hip_runtime.h>

#define IN_DIM 128
#define F1 256      // HEADS*HID = 4*64
#define HID 64
#define OUT_DIM 32
#define NEG 0.2f
#define PADK 136    // LDS row pitch in bf16 elems (128 + 8): frag reads 2-way alias = free

typedef __attribute__((ext_vector_type(8))) short short8;
typedef __attribute__((ext_vector_type(4))) float v4f;
typedef __attribute__((ext_vector_type(2))) float v2f;

// ---- bf16 helpers ----
__device__ __forceinline__ float b2fl(unsigned u) {
  union { unsigned i; float f; } c; c.i = u << 16; return c.f;
}
__device__ __forceinline__ float b2fh(unsigned u) {
  union { unsigned i; float f; } c; c.i = u & 0xffff0000u; return c.f;
}
__device__ __forceinline__ unsigned short f2b(float f) {
  union { float f; unsigned i; } c; c.f = f;
  unsigned r = c.i + 0x7fffu + ((c.i >> 16) & 1u);   // RNE
  return (unsigned short)(r >> 16);
}

// ---- merged prep + hist ----
__global__ __launch_bounds__(256) void k_prep_hist(const float* __restrict__ W1,
    unsigned short* __restrict__ W1t, const float* __restrict__ W2,
    unsigned short* __restrict__ W2t, const int* __restrict__ adj,
    int* __restrict__ cnt, int* __restrict__ rank, int E_, int n) {
  const int b = blockIdx.x;
  if (b < 128) {            // W1t[n][k] = W1[k][n], 32768 elems
    int idx = b * 256 + threadIdx.x;
    int nn = idx >> 7, k = idx & 127;
    W1t[idx] = f2b(W1[(size_t)k * F1 + nn]);
    return;
  }
  if (b < 160) {            // W2t[n][k] = W2[k][n], 8192 elems
    int idx = (b - 128) * 256 + threadIdx.x;
    int nn = idx >> 8, k = idx & 255;
    W2t[idx] = f2b(W2[(size_t)k * OUT_DIM + nn]);
    return;
  }
  int e = (b - 160) * 256 + threadIdx.x;
  int ET = E_ + n;
  if (e >= ET) return;
  int d = (e < E_) ? adj[E_ + e] : (e - E_);
  rank[e] = atomicAdd(&cnt[d], 1);
}

// ------- GEMM1 via MFMA: h1f8[N,256](fp8 e4m3) = bf16(x)[N,128] @ W1[128,256] -------
// LDS-staged W per head (R4: direct-global W frags serialized 200-cyc L2 loads
// into the MFMA chain at ~2 blocks/CU -> 45 µs vs 25 µs staged).
__global__ __launch_bounds__(256) void k_gemm1(const float* __restrict__ x,
    const unsigned short* __restrict__ W1t,
    const float* __restrict__ a1s_w, const float* __restrict__ a1d_w,
    unsigned char* __restrict__ h1f8, float* __restrict__ as1,
    float* __restrict__ ad1, int n) {
  __shared__ unsigned short xs[64 * PADK];   // 17.4 KB
  __shared__ unsigned short ws[64 * PADK];   // 17.4 KB (reused per head)
  const int tid = threadIdx.x;
  const int rb = blockIdx.x * 64;

#pragma unroll
  for (int i = 0; i < 8; ++i) {
    int idx = tid + i * 256;
    int row = idx >> 5, c4 = idx & 31;
    float4 v = make_float4(0.f, 0.f, 0.f, 0.f);
    if (rb + row < n) v = *(const float4*)&x[(size_t)(rb + row) * IN_DIM + c4 * 4];
    ushort4 b; b.x = f2b(v.x); b.y = f2b(v.y); b.z = f2b(v.z); b.w = f2b(v.w);
    *(ushort4*)&xs[row * PADK + c4 * 4] = b;
  }

  const int wv = tid >> 6;
  const int lane = tid & 63;
  const int l15 = lane & 15, quad = lane >> 4;

  for (int head = 0; head < 4; ++head) {
    const int cb = head * 64;
#pragma unroll
    for (int i = 0; i < 4; ++i) {
      int idx = tid + i * 256;
      int row = idx >> 4, c = idx & 15;
      *(uint4*)&ws[row * PADK + c * 8] =
          *(const uint4*)&W1t[(size_t)(cb + row) * IN_DIM + c * 8];
    }
    __syncthreads();

    v4f acc0 = {0.f, 0.f, 0.f, 0.f}, acc1 = acc0, acc2 = acc0, acc3 = acc0;
#pragma unroll
    for (int kt = 0; kt < 4; ++kt) {
      const int ko = kt * 32 + quad * 8;
      short8 af = *(const short8*)&xs[(wv * 16 + l15) * PADK + ko];
      short8 b0 = *(const short8*)&ws[(l15) * PADK + ko];
      short8 b1 = *(const short8*)&ws[(16 + l15) * PADK + ko];
      short8 b2 = *(const short8*)&ws[(32 + l15) * PADK + ko];
      short8 b3 = *(const short8*)&ws[(48 + l15) * PADK + ko];
      acc0 = __builtin_amdgcn_mfma_f32_16x16x32_bf16(af, b0, acc0, 0, 0, 0);
      acc1 = __builtin_amdgcn_mfma_f32_16x16x32_bf16(af, b1, acc1, 0, 0, 0);
      acc2 = __builtin_amdgcn_mfma_f32_16x16x32_bf16(af, b2, acc2, 0, 0, 0);
      acc3 = __builtin_amdgcn_mfma_f32_16x16x32_bf16(af, b3, acc3, 0, 0, 0);
    }

    const float s0 = a1s_w[cb + l15],      s1 = a1s_w[cb + 16 + l15];
    const float s2 = a1s_w[cb + 32 + l15], s3 = a1s_w[cb + 48 + l15];
    const float d0 = a1d_w[cb + l15],      d1 = a1d_w[cb + 16 + l15];
    const float d2 = a1d_w[cb + 32 + l15], d3 = a1d_w[cb + 48 + l15];
#pragma unroll
    for (int r = 0; r < 4; ++r) {
      const int row = rb + wv * 16 + quad * 4 + r;
      const bool ok = row < n;
      if (ok) {
        size_t base = (size_t)row * F1 + cb;
        int pA = __builtin_amdgcn_cvt_pk_fp8_f32(acc0[r], acc1[r], 0, false);
        int pB = __builtin_amdgcn_cvt_pk_fp8_f32(acc2[r], acc3[r], 0, false);
        h1f8[base + l15]      = (unsigned char)(pA & 0xff);
        h1f8[base + 16 + l15] = (unsigned char)((pA >> 8) & 0xff);
        h1f8[base + 32 + l15] = (unsigned char)(pB & 0xff);
        h1f8[base + 48 + l15] = (unsigned char)((pB >> 8) & 0xff);
      }
      float ds = acc0[r] * s0 + acc1[r] * s1 + acc2[r] * s2 + acc3[r] * s3;
      float dd = acc0[r] * d0 + acc1[r] * d1 + acc2[r] * d2 + acc3[r] * d3;
#pragma unroll
      for (int m = 1; m <= 8; m <<= 1) {
        ds += __shfl_xor(ds, m, 64);
        dd += __shfl_xor(dd, m, 64);
      }
      if (ok && l15 == 0) {
        as1[(size_t)row * 4 + head] = ds;
        ad1[(size_t)row * 4 + head] = dd;
      }
    }
    __syncthreads();   // ws reuse barrier (LDS reads done before next stage)
  }
}

// scan phase A: per-1024-chunk local exclusive scan + chunk sums; block 0 also
// zeroes gsum/gcnt (consumed by k_pool much later).
__global__ __launch_bounds__(256) void k_scan_local(const int* __restrict__ cnt,
    int* __restrict__ offs, int* __restrict__ bsum,
    float* __restrict__ gsum, float* __restrict__ gcnt, int n) {
  __shared__ int wsums[4];
  const int tid = threadIdx.x;
  if (blockIdx.x == 0 && tid < 64) { gsum[tid] = 0.f; gcnt[tid] = 0.f; }
  const int lane = tid & 63, w = tid >> 6;
  const int base = blockIdx.x * 1024;
  const int i0 = base + tid * 4;
  int v[4];
#pragma unroll
  for (int k = 0; k < 4; ++k) { int i = i0 + k; v[k] = (i < n) ? cnt[i] : 0; }
  int tsum = v[0] + v[1] + v[2] + v[3];
  int incl = tsum;
#pragma unroll
  for (int d = 1; d < 64; d <<= 1) {
    int t = __shfl_up(incl, (unsigned)d, 64);
    if (lane >= d) incl += t;
  }
  if (lane == 63) wsums[w] = incl;
  __syncthreads();
  int pre = 0;
  for (int k = 0; k < w; ++k) pre += wsums[k];
  int run = pre + incl - tsum;
#pragma unroll
  for (int k = 0; k < 4; ++k) { int i = i0 + k; if (i < n) offs[i] = run; run += v[k]; }
  if (tid == 255) bsum[blockIdx.x] = pre + incl;
}

// scan phase B (merged bsum-scan + add)
__global__ __launch_bounds__(256) void k_scan_add(int* __restrict__ offs,
    const int* __restrict__ bsum, int n, int nb) {
  __shared__ int pre_s, tot_s;
  const int tid = threadIdx.x;
  if (tid < 64) {
    int v = (tid < nb) ? bsum[tid] : 0;
    int incl = v;
#pragma unroll
    for (int d = 1; d < 64; d <<= 1) {
      int t = __shfl_up(incl, (unsigned)d, 64);
      if (tid >= d) incl += t;
    }
    int excl = incl - v;
    int pre = __shfl(excl, blockIdx.x >> 2, 64);
    int tot = __shfl(incl, nb - 1, 64);
    if (tid == 0) { pre_s = pre; tot_s = tot; }
  }
  __syncthreads();
  int i = blockIdx.x * 256 + tid;
  if (i < n) offs[i] += pre_s;
  if (blockIdx.x == 0 && tid == 0) offs[n] = tot_s;
}

// -------- scatter, atomic-free; record = src only (4B). Weights are computed
// inline in the agg kernels (ad*[dst] is wave-uniform there). 4 dst-bins.
__global__ __launch_bounds__(256) void k_scatter(const int* __restrict__ adj,
    const int* __restrict__ rank, const int* __restrict__ offs,
    int* __restrict__ csrsrc, int E_, int n, int binw) {
  const int bin = blockIdx.x & 3;
  const int chunk = blockIdx.x >> 2;
  const int e = chunk * 256 + threadIdx.x;
  const int ET = E_ + n;
  if (e >= ET) return;
  int d = (e < E_) ? adj[E_ + e] : (e - E_);
  const int lo = bin * binw;
  if (d < lo || d >= lo + binw) return;   // not my bin
  int s = (e < E_) ? adj[e] : d;
  int pos = offs[d] + rank[e];
  csrsrc[pos] = s;
}

// fp8 row accumulate: 8 packed-pair FMAs off the packed cvt_pk_f32_fp8 results.
__device__ __forceinline__ void acc8_fp8(v2f acc[8], const uint4 u, float w) {
  v2f w2; w2.x = w; w2.y = w;
  acc[0] += w2 * __builtin_amdgcn_cvt_pk_f32_fp8(u.x, false);
  acc[1] += w2 * __builtin_amdgcn_cvt_pk_f32_fp8(u.x, true);
  acc[2] += w2 * __builtin_amdgcn_cvt_pk_f32_fp8(u.y, false);
  acc[3] += w2 * __builtin_amdgcn_cvt_pk_f32_fp8(u.y, true);
  acc[4] += w2 * __builtin_amdgcn_cvt_pk_f32_fp8(u.z, false);
  acc[5] += w2 * __builtin_amdgcn_cvt_pk_f32_fp8(u.z, true);
  acc[6] += w2 * __builtin_amdgcn_cvt_pk_f32_fp8(u.w, false);
  acc[7] += w2 * __builtin_amdgcn_cvt_pk_f32_fp8(u.w, true);
}

// ------- fused GAT layer 1 (fp8 gather, quarter-wave per edge, inline weights) -------
// R7: back to 8-wide main loop (R6's 16-wide chains collapsed occupancy 57->34%:
// TLP > ILP here) + index loads rotated one trip ahead (clamped, branch-free) to
// take csrsrc latency off the per-trip critical chain.
__global__ __launch_bounds__(256) void k_agg1(const unsigned char* __restrict__ h1f8,
    const int* __restrict__ offs, const int* __restrict__ csrsrc,
    const float* __restrict__ as1, const float* __restrict__ ad1,
    const float* __restrict__ b1, unsigned short* __restrict__ relu1b, int n) {
  int node = blockIdx.x * 4 + (threadIdx.x >> 6);
  int lane = threadIdx.x & 63;
  if (node >= n) return;
  const int sub = lane >> 4;       // edge slot within group of 4
  const int p = lane & 15;         // feature 16-tuple
  const int h = p >> 2;            // head
  const float ad1n = ad1[(size_t)node * 4 + h];   // dst term: wave-uniform per head
  const int j0 = offs[node], j1 = offs[node + 1];
  v2f acc[8];
#pragma unroll
  for (int i = 0; i < 8; ++i) { acc[i].x = 0.f; acc[i].y = 0.f; }
  float den = 0.f;
  int j = j0;
  const int jlast = j1 - 1;
  // rotated index prefetch (safe clamp; j0<j1 always since self-loop exists)
  int nsA = csrsrc[min(j + sub, jlast)];
  int nsB = csrsrc[min(j + 4 + sub, jlast)];
  for (; j + 8 <= j1; j += 8) {
    const int sA = nsA;
    const int sB = nsB;
    // issue next trip's index loads immediately (clamped; no branch)
    nsA = csrsrc[min(j + 8 + sub, jlast)];
    nsB = csrsrc[min(j + 12 + sub, jlast)];
    const uint4 uA = ((const uint4*)(h1f8 + (size_t)sA * F1))[p];
    const uint4 uB = ((const uint4*)(h1f8 + (size_t)sB * F1))[p];
    float ev;
    ev = as1[(size_t)sA * 4 + h] + ad1n;
    ev = (ev >= 0.f) ? ev : NEG * ev;
    const float wA = __expf(ev);
    den += wA;
    acc8_fp8(acc, uA, wA);
    ev = as1[(size_t)sB * 4 + h] + ad1n;
    ev = (ev >= 0.f) ? ev : NEG * ev;
    const float wB = __expf(ev);
    den += wB;
    acc8_fp8(acc, uB, wB);
  }
  for (; j < j1; j += 4) {
    const int idx = j + sub;
    const bool valid = idx < j1;
    const int s = csrsrc[valid ? idx : jlast];
    const uint4 u = ((const uint4*)(h1f8 + (size_t)s * F1))[p];
    float ev = as1[(size_t)s * 4 + h] + ad1n;
    ev = (ev >= 0.f) ? ev : NEG * ev;
    float w = valid ? __expf(ev) : 0.f;
    den += w;
    acc8_fp8(acc, u, w);
  }
  den += __shfl_xor(den, 16, 64); den += __shfl_xor(den, 32, 64);
#pragma unroll
  for (int i = 0; i < 8; ++i) {
    acc[i].x += __shfl_xor(acc[i].x, 16, 64);
    acc[i].x += __shfl_xor(acc[i].x, 32, 64);
    acc[i].y += __shfl_xor(acc[i].y, 16, 64);
    acc[i].y += __shfl_xor(acc[i].y, 32, 64);
  }
  if (sub == 0) {
    const float inv = 1.0f / den;
    float a[16];
#pragma unroll
    for (int i = 0; i < 8; ++i) { a[2 * i] = acc[i].x; a[2 * i + 1] = acc[i].y; }
    ushort4 r0, r1, r2, r3;
    const float4 bb0 = ((const float4*)b1)[4 * p + 0];
    const float4 bb1 = ((const float4*)b1)[4 * p + 1];
    const float4 bb2 = ((const float4*)b1)[4 * p + 2];
    const float4 bb3 = ((const float4*)b1)[4 * p + 3];
    r0.x = f2b(fmaxf(a[0] * inv + bb0.x, 0.f));
    r0.y = f2b(fmaxf(a[1] * inv + bb0.y, 0.f));
    r0.z = f2b(fmaxf(a[2] * inv + bb0.z, 0.f));
    r0.w = f2b(fmaxf(a[3] * inv + bb0.w, 0.f));
    r1.x = f2b(fmaxf(a[4] * inv + bb1.x, 0.f));
    r1.y = f2b(fmaxf(a[5] * inv + bb1.y, 0.f));
    r1.z = f2b(fmaxf(a[6] * inv + bb1.z, 0.f));
    r1.w = f2b(fmaxf(a[7] * inv + bb1.w, 0.f));
    r2.x = f2b(fmaxf(a[8] * inv + bb2.x, 0.f));
    r2.y = f2b(fmaxf(a[9] * inv + bb2.y, 0.f));
    r2.z = f2b(fmaxf(a[10] * inv + bb2.z, 0.f));
    r2.w = f2b(fmaxf(a[11] * inv + bb2.w, 0.f));
    r3.x = f2b(fmaxf(a[12] * inv + bb3.x, 0.f));
    r3.y = f2b(fmaxf(a[13] * inv + bb3.y, 0.f));
    r3.z = f2b(fmaxf(a[14] * inv + bb3.z, 0.f));
    r3.w = f2b(fmaxf(a[15] * inv + bb3.w, 0.f));
    size_t base = (size_t)node * F1 + 16 * p;
    *(ushort4*)&relu1b[base + 0]  = r0;
    *(ushort4*)&relu1b[base + 4]  = r1;
    *(ushort4*)&relu1b[base + 8]  = r2;
    *(ushort4*)&relu1b[base + 12] = r3;
  }
}

// ---- GEMM2 via MFMA: h2[N,32] = relu1b(bf16) @ W2t(bf16); fused alpha2 dots ----
__global__ __launch_bounds__(256) void k_gemm2(const unsigned short* __restrict__ relu1b,
    const unsigned short* __restrict__ W2t, const float* __restrict__ a2s_w,
    const float* __restrict__ a2d_w, unsigned short* __restrict__ h2b,
    float* __restrict__ as2, float* __restrict__ ad2, int n) {
  const int tid = threadIdx.x;
  const int wv = tid >> 6, lane = tid & 63;
  const int l15 = lane & 15, quad = lane >> 4;
  const int row0 = blockIdx.x * 64 + wv * 16;
  v4f acc0 = {0.f, 0.f, 0.f, 0.f}, acc1 = acc0;
  const int arow = row0 + l15;
  const bool aok = arow < n;
#pragma unroll
  for (int kt = 0; kt < 8; ++kt) {
    const int ko = kt * 32 + quad * 8;
    short8 af = {0, 0, 0, 0, 0, 0, 0, 0};
    if (aok) af = *(const short8*)&relu1b[(size_t)arow * F1 + ko];
    short8 b0 = *(const short8*)&W2t[(size_t)l15 * F1 + ko];
    short8 b1 = *(const short8*)&W2t[(size_t)(16 + l15) * F1 + ko];
    acc0 = __builtin_amdgcn_mfma_f32_16x16x32_bf16(af, b0, acc0, 0, 0, 0);
    acc1 = __builtin_amdgcn_mfma_f32_16x16x32_bf16(af, b1, acc1, 0, 0, 0);
  }
  const float s0 = a2s_w[l15], s1 = a2s_w[16 + l15];
  const float d0 = a2d_w[l15], d1 = a2d_w[16 + l15];
#pragma unroll
  for (int r = 0; r < 4; ++r) {
    const int row = row0 + quad * 4 + r;
    const bool ok = row < n;
    if (ok) {
      h2b[(size_t)row * OUT_DIM + l15]      = f2b(acc0[r]);
      h2b[(size_t)row * OUT_DIM + 16 + l15] = f2b(acc1[r]);
    }
    float ss = acc0[r] * s0 + acc1[r] * s1;
    float sd = acc0[r] * d0 + acc1[r] * d1;
#pragma unroll
    for (int m = 1; m <= 8; m <<= 1) {
      ss += __shfl_xor(ss, m, 64);
      sd += __shfl_xor(sd, m, 64);
    }
    if (ok && l15 == 0) { as2[row] = ss; ad2[row] = sd; }
  }
}

// -------- fused GAT layer 2 + log_softmax + lin -> per-node score --------
// 8-lane edge groups (uint2 row loads), R5 loop structure + rotated index
// prefetch (R7).
__global__ __launch_bounds__(256) void k_agg2(const unsigned short* __restrict__ h2b,
    const int* __restrict__ csrsrc, const int* __restrict__ offs,
    const float* __restrict__ as2, const float* __restrict__ ad2,
    const float* __restrict__ b2, const float* __restrict__ linW,
    float* __restrict__ score, int n) {
  int node = blockIdx.x * 4 + (threadIdx.x >> 6);
  int lane = threadIdx.x & 63;
  if (node >= n) return;
  const int grp = lane >> 3;      // edge slot within group of 8
  const int p = lane & 7;         // dword-pair index (dims 4p..4p+3)
  const float ad2n = ad2[node];   // dst term: wave-uniform
  const int j0 = offs[node], j1 = offs[node + 1];
  const int jlast = j1 - 1;
  v2f aX = {0.f, 0.f}, aY = {0.f, 0.f};
  float den = 0.f;
  int jj = j0;
  int nsA = csrsrc[min(jj + grp, jlast)];
  int nsB = csrsrc[min(jj + 8 + grp, jlast)];
  for (; jj + 16 <= j1; jj += 16) {
    const int sA = nsA;
    const int sB = nsB;
    nsA = csrsrc[min(jj + 16 + grp, jlast)];
    nsB = csrsrc[min(jj + 24 + grp, jlast)];
    const uint2 uA = ((const uint2*)(h2b + (size_t)sA * OUT_DIM))[p];
    const uint2 uB = ((const uint2*)(h2b + (size_t)sB * OUT_DIM))[p];
    float ev;
    ev = as2[sA] + ad2n; ev = (ev >= 0.f) ? ev : NEG * ev;
    const float wA = __expf(ev);
    ev = as2[sB] + ad2n; ev = (ev >= 0.f) ? ev : NEG * ev;
    const float wB = __expf(ev);
    den += wA + wB;
    v2f wA2; wA2.x = wA; wA2.y = wA;
    v2f wB2; wB2.x = wB; wB2.y = wB;
    v2f vx, vy;
    vx.x = b2fl(uA.x); vx.y = b2fh(uA.x); aX += wA2 * vx;
    vy.x = b2fl(uA.y); vy.y = b2fh(uA.y); aY += wA2 * vy;
    vx.x = b2fl(uB.x); vx.y = b2fh(uB.x); aX += wB2 * vx;
    vy.x = b2fl(uB.y); vy.y = b2fh(uB.y); aY += wB2 * vy;
  }
  for (; jj < j1; jj += 8) {
    const int idx = jj + grp;
    const bool valid = idx < j1;
    const int s = csrsrc[valid ? idx : jlast];
    const uint2 u = ((const uint2*)(h2b + (size_t)s * OUT_DIM))[p];
    float ev = as2[s] + ad2n; ev = (ev >= 0.f) ? ev : NEG * ev;
    float w = valid ? __expf(ev) : 0.f;
    den += w;
    v2f w2; w2.x = w; w2.y = w;
    v2f vx, vy;
    vx.x = b2fl(u.x); vx.y = b2fh(u.x); aX += w2 * vx;
    vy.x = b2fl(u.y); vy.y = b2fh(u.y); aY += w2 * vy;
  }
  float a0 = aX.x, a1 = aX.y, a2 = aY.x, a3 = aY.y;
  // reduce across the 8 edge-groups (lane bits 3..5)
#pragma unroll
  for (int m = 8; m <= 32; m <<= 1) {
    den += __shfl_xor(den, m, 64);
    a0  += __shfl_xor(a0, m, 64);
    a1  += __shfl_xor(a1, m, 64);
    a2  += __shfl_xor(a2, m, 64);
    a3  += __shfl_xor(a3, m, 64);
  }
  const float inv = 1.0f / den;
  const float4 bb = ((const float4*)b2)[p];
  float o0 = a0 * inv + bb.x;
  float o1 = a1 * inv + bb.y;
  float o2 = a2 * inv + bb.z;
  float o3 = a3 * inv + bb.w;
  float m = fmaxf(fmaxf(o0, o1), fmaxf(o2, o3));
#pragma unroll
  for (int mm = 1; mm <= 4; mm <<= 1) m = fmaxf(m, __shfl_xor(m, mm, 64));
  float ssum = __expf(o0 - m) + __expf(o1 - m) + __expf(o2 - m) + __expf(o3 - m);
#pragma unroll
  for (int mm = 1; mm <= 4; mm <<= 1) ssum += __shfl_xor(ssum, mm, 64);
  const float lse = m + __logf(ssum);
  const float4 lw = ((const float4*)linW)[p];
  float sc = (o0 - lse) * lw.x + (o1 - lse) * lw.y + (o2 - lse) * lw.z + (o3 - lse) * lw.w;
#pragma unroll
  for (int mm = 1; mm <= 4; mm <<= 1) sc += __shfl_xor(sc, mm, 64);
  if (lane == 0) score[node] = sc;
}

// -------- pooling: LDS per-graph partials, few global atomics per block --------
// (two-stage on purpose: fusing atomics into k_agg2 serialized 100K RMWs onto
//  4 cachelines of gsum/gcnt -> +390 µs.)
__global__ __launch_bounds__(256) void k_pool(const float* __restrict__ score,
    const int* __restrict__ batch, float* __restrict__ gsum,
    float* __restrict__ gcnt, int n) {
  __shared__ float ps[64];
  __shared__ float pc[64];
  const int tid = threadIdx.x;
  if (tid < 64) { ps[tid] = 0.f; pc[tid] = 0.f; }
  __syncthreads();
  int i = blockIdx.x * 256 + tid;
  if (i < n) {
    int g = batch[i];
    atomicAdd(&ps[g], score[i]);
    atomicAdd(&pc[g], 1.0f);
  }
  __syncthreads();
  if (tid < 64 && pc[tid] != 0.f) {
    atomicAdd(&gsum[tid], ps[tid]);
    atomicAdd(&gcnt[tid], pc[tid]);
  }
}

__global__ void k_final(const float* __restrict__ gsum, const float* __restrict__ gcnt,
                        const float* __restrict__ linb, float* __restrict__ out, int g_) {
  int g = threadIdx.x;
  if (g < g_) out[g] = gsum[g] / fmaxf(gcnt[g], 1.0f) + linb[0];
}

extern "C" void kernel_launch(void* const* d_in, const int* in_sizes, int n_in,
                              void* d_out, int out_size, void* d_ws, size_t ws_size,
                              hipStream_t stream) {
  const float* x    = (const float*)d_in[0];
  const int*   adj  = (const int*)d_in[1];
  const int*   batch= (const int*)d_in[2];
  const float* W1   = (const float*)d_in[3];
  const float* a1s  = (const float*)d_in[4];
  const float* a1d  = (const float*)d_in[5];
  const float* b1   = (const float*)d_in[6];
  const float* W2   = (const float*)d_in[7];
  const float* a2s  = (const float*)d_in[8];
  const float* a2d  = (const float*)d_in[9];
  const float* b2   = (const float*)d_in[10];
  const float* linW = (const float*)d_in[11];
  const float* linb = (const float*)d_in[12];

  const int N = in_sizes[0] / IN_DIM;
  const int E = in_sizes[1] / 2;
  const int ET = E + N;
  const int G = out_size;   // 64
  const int NB = (N + 1023) / 1024;   // must be <= 64 for merged scan (N=50000 -> 49)
  const int BINW = (N + 3) / 4;

  char* wsb = (char*)d_ws;
  size_t off = 0;
  auto take = [&](size_t bytes) -> char* {
    char* p = wsb + off;
    off += (bytes + 255) & ~(size_t)255;
    return p;
  };
  unsigned char* h1f8  = (unsigned char*)take((size_t)N * F1);
  unsigned short* relu1b= (unsigned short*)take((size_t)N * F1 * 2);
  float* as1    = (float*)take((size_t)N * 4 * 4);
  float* ad1    = (float*)take((size_t)N * 4 * 4);
  unsigned short* h2b = (unsigned short*)take((size_t)N * OUT_DIM * 2);
  float* as2v   = (float*)take((size_t)N * 4);
  float* ad2v   = (float*)take((size_t)N * 4);
  float* score  = (float*)take((size_t)N * 4);
  int*   cnt    = (int*)take((size_t)N * 4);
  int*   offs   = (int*)take((size_t)(N + 1) * 4);
  int*   rank   = (int*)take((size_t)ET * 4);
  int*   csrsrc = (int*)take((size_t)ET * 4);
  int*   bsum   = (int*)take((size_t)(NB + 1) * 4);
  float* gsum   = (float*)take((size_t)G * 4);
  float* gcnt   = (float*)take((size_t)G * 4);
  unsigned short* W1t = (unsigned short*)take((size_t)IN_DIM * F1 * 2);
  unsigned short* W2t = (unsigned short*)take((size_t)F1 * OUT_DIM * 2);
  (void)ws_size; (void)n_in;

  hipMemsetAsync(cnt, 0, (size_t)N * 4, stream);

  dim3 b256(256);
  k_prep_hist<<<dim3(160 + (ET + 255) / 256), b256, 0, stream>>>(
      W1, W1t, W2, W2t, adj, cnt, rank, E, N);
  k_gemm1<<<dim3((N + 63) / 64), b256, 0, stream>>>(x, W1t, a1s, a1d, h1f8, as1, ad1, N);
  k_scan_local<<<dim3(NB), b256, 0, stream>>>(cnt, offs, bsum, gsum, gcnt, N);
  k_scan_add<<<dim3((N + 255) / 256), b256, 0, stream>>>(offs, bsum, N, NB);
  k_scatter<<<dim3(((ET + 255) / 256) * 4), b256, 0, stream>>>(adj, rank, offs, csrsrc, E, N, BINW);
  k_agg1<<<dim3((N + 3) / 4), b256, 0, stream>>>(h1f8, offs, csrsrc, as1, ad1, b1, relu1b, N);
  k_gemm2<<<dim3((N + 63) / 64), b256, 0, stream>>>(relu1b, W2t, a2s, a2d, h2b, as2v, ad2v, N);
  k_agg2<<<dim3((N + 3) / 4), b256, 0, stream>>>(h2b, csrsrc, offs, as2v, ad2v, b2, linW,
                                                 score, N);
  k_pool<<<dim3((N + 255) / 256), b256, 0, stream>>>(score, batch, gsum, gcnt, N);
  k_final<<<1, 64, 0, stream>>>(gsum, gcnt, linb, (float*)d_out, G);
}